// Round 1
// baseline (50.682 us; speedup 1.0000x reference)
//
#include <hip/hip_runtime.h>

// NeuralAdditiveModel: out[b] = bias + sum_f ( b2[f] + sum_h relu(x[b,f]*W1[f,h]+b1[f,h]) * W2[f,h] )
// x: [16384, 1024] f32, W1/b1/W2: [1024,16] f32, b2: [1024], bias: [1]. out: [16384] f32.

constexpr int BATCH = 16384;
constexpr int NF    = 1024;
constexpr int HID   = 16;

constexpr int BLOCK  = 256;             // threads per block; each thread owns 1 row
constexpr int ROWS   = 256;             // rows per block
constexpr int FSPLIT = 16;              // feature-dim split across blocks
constexpr int FCHUNK = NF / FSPLIT;     // 64 features per block
constexpr int FSUB   = 32;              // features staged per LDS tile
constexpr int NSUB   = FCHUNK / FSUB;   // 2 staging iterations
constexpr int LSTR   = FSUB + 4;        // 36 floats: keeps 16B alignment, spreads banks
constexpr int ROWBLOCKS = BATCH / ROWS; // 64

__global__ __launch_bounds__(BLOCK) void nam_init(float* __restrict__ out,
                                                  const float* __restrict__ bias) {
    int i = blockIdx.x * BLOCK + threadIdx.x;
    if (i < BATCH) out[i] = bias[0];
}

__global__ __launch_bounds__(BLOCK) void nam_main(const float* __restrict__ x,
                                                  const float* __restrict__ W1,
                                                  const float* __restrict__ b1,
                                                  const float* __restrict__ W2,
                                                  const float* __restrict__ b2,
                                                  float* __restrict__ out) {
    __shared__ float xs[ROWS * LSTR];

    const int tid   = threadIdx.x;
    const int rb    = blockIdx.x % ROWBLOCKS;   // row block
    const int fc    = blockIdx.x / ROWBLOCKS;   // feature chunk
    const int row0  = rb * ROWS;
    const int fbase = fc * FCHUNK;

    float acc = 0.0f;

    for (int s = 0; s < NSUB; ++s) {
        const int f0 = fbase + s * FSUB;

        __syncthreads();  // protect xs from previous iteration's readers
        // Stage x[row0 .. row0+256)[f0 .. f0+32) -> xs, coalesced 128B-per-8-lane segments.
        #pragma unroll
        for (int i = 0; i < (ROWS * FSUB / 4) / BLOCK; ++i) {   // 8 float4s per thread
            const int j  = i * BLOCK + tid;       // linear float4 index in tile
            const int r  = j >> 3;                // 8 float4 per row
            const int c4 = j & 7;
            const float4 v = *reinterpret_cast<const float4*>(
                x + (size_t)(row0 + r) * NF + f0 + c4 * 4);
            *reinterpret_cast<float4*>(&xs[r * LSTR + c4 * 4]) = v;
        }
        __syncthreads();

        // Compute: thread owns row `tid`; feature index is wave-uniform -> params via s_load.
        #pragma unroll 4
        for (int fl = 0; fl < FSUB; ++fl) {
            const int f = f0 + fl;
            const float xv = xs[tid * LSTR + fl];
            const float* __restrict__ w1 = W1 + f * HID;
            const float* __restrict__ bb = b1 + f * HID;
            const float* __restrict__ w2 = W2 + f * HID;
            float c0 = 0.f, c1 = 0.f, c2 = 0.f, c3 = 0.f;
            #pragma unroll
            for (int h = 0; h < HID; h += 4) {
                const float z0 = fmaxf(fmaf(xv, w1[h + 0], bb[h + 0]), 0.f);
                const float z1 = fmaxf(fmaf(xv, w1[h + 1], bb[h + 1]), 0.f);
                const float z2 = fmaxf(fmaf(xv, w1[h + 2], bb[h + 2]), 0.f);
                const float z3 = fmaxf(fmaf(xv, w1[h + 3], bb[h + 3]), 0.f);
                c0 = fmaf(z0, w2[h + 0], c0);
                c1 = fmaf(z1, w2[h + 1], c1);
                c2 = fmaf(z2, w2[h + 2], c2);
                c3 = fmaf(z3, w2[h + 3], c3);
            }
            acc += (c0 + c1) + (c2 + c3) + b2[f];
        }
    }

    atomicAdd(&out[row0 + tid], acc);
}

extern "C" void kernel_launch(void* const* d_in, const int* in_sizes, int n_in,
                              void* d_out, int out_size, void* d_ws, size_t ws_size,
                              hipStream_t stream) {
    const float* x    = (const float*)d_in[0];
    const float* W1   = (const float*)d_in[1];
    const float* b1   = (const float*)d_in[2];
    const float* W2   = (const float*)d_in[3];
    const float* b2   = (const float*)d_in[4];
    const float* bias = (const float*)d_in[5];
    float* out = (float*)d_out;

    nam_init<<<BATCH / BLOCK, BLOCK, 0, stream>>>(out, bias);
    nam_main<<<ROWBLOCKS * FSPLIT, BLOCK, 0, stream>>>(x, W1, b1, W2, b2, out);
}

// Round 2
// 36.749 us; speedup vs baseline: 1.3792x; 1.3792x over previous
//
#include <hip/hip_runtime.h>

// NeuralAdditiveModel: out[b] = bias + sum_f ( b2[f] + sum_h relu(x[b,f]*W1[f,h]+b1[f,h]) * W2[f,h] )
// x: [16384, 1024] f32, W1/b1/W2: [1024,16] f32, b2: [1024], bias: [1]. out: [16384] f32.
//
// Mapping: lane owns a FEATURE (params in 48 VGPRs, loaded once per block),
// loops over rows; x reads coalesced; feature-sum via two-level LDS reduce.

constexpr int BATCH = 16384;
constexpr int NF    = 1024;
constexpr int HID   = 16;

constexpr int BLOCK = 256;         // threads per block
constexpr int FG    = 4;           // feature-dim split: 4 blocks cover 1024 features
constexpr int FPB   = NF / FG;     // 256 features per block (== BLOCK, 1 per thread)
constexpr int R     = 64;          // rows per block
constexpr int PR    = 32;          // rows per LDS-reduce phase
constexpr int RB    = BATCH / R;   // 256 row blocks
constexpr int LD    = BLOCK + 1;   // 257: odd stride -> conflict-free column reads

__global__ __launch_bounds__(BLOCK) void nam_init(float* __restrict__ out,
                                                  const float* __restrict__ bias) {
    int i = blockIdx.x * BLOCK + threadIdx.x;
    if (i < BATCH) out[i] = bias[0];
}

__global__ __launch_bounds__(BLOCK) void nam_main(const float* __restrict__ x,
                                                  const float* __restrict__ W1,
                                                  const float* __restrict__ b1,
                                                  const float* __restrict__ W2,
                                                  const float* __restrict__ b2,
                                                  float* __restrict__ out) {
    __shared__ float part[PR][LD];      // per-(row,lane) partial sums
    __shared__ float part2[PR][9];      // level-2 partials (pad 9: odd-ish stride)

    const int tid  = threadIdx.x;
    const int rb   = blockIdx.x & (RB - 1);   // row block
    const int fg   = blockIdx.x >> 8;         // feature group (blockIdx.x / RB)
    const int row0 = rb * R;
    const int f    = fg * FPB + tid;          // this lane's feature

    // ---- load this feature's params into VGPRs (once per block) ----
    float w1[HID], bb[HID], w2[HID];
    #pragma unroll
    for (int i = 0; i < HID / 4; ++i) {
        *reinterpret_cast<float4*>(&w1[4 * i]) =
            *reinterpret_cast<const float4*>(W1 + (size_t)f * HID + 4 * i);
        *reinterpret_cast<float4*>(&bb[4 * i]) =
            *reinterpret_cast<const float4*>(b1 + (size_t)f * HID + 4 * i);
        *reinterpret_cast<float4*>(&w2[4 * i]) =
            *reinterpret_cast<const float4*>(W2 + (size_t)f * HID + 4 * i);
    }
    const float b2f = b2[f];

    for (int ph = 0; ph < R; ph += PR) {
        // ---- compute phase: PR rows, all-VGPR inner loop (3 ops per h) ----
        #pragma unroll 4
        for (int r = 0; r < PR; ++r) {
            const int row = row0 + ph + r;
            const float xv = x[(size_t)row * NF + f];   // coalesced: lanes -> consecutive f
            float g0 = 0.f, g1 = 0.f, g2 = 0.f, g3 = 0.f;
            #pragma unroll
            for (int h = 0; h < HID; h += 4) {
                g0 = fmaf(fmaxf(fmaf(xv, w1[h + 0], bb[h + 0]), 0.f), w2[h + 0], g0);
                g1 = fmaf(fmaxf(fmaf(xv, w1[h + 1], bb[h + 1]), 0.f), w2[h + 1], g1);
                g2 = fmaf(fmaxf(fmaf(xv, w1[h + 2], bb[h + 2]), 0.f), w2[h + 2], g2);
                g3 = fmaf(fmaxf(fmaf(xv, w1[h + 3], bb[h + 3]), 0.f), w2[h + 3], g3);
            }
            part[r][tid] = ((g0 + g1) + (g2 + g3)) + b2f;
        }
        __syncthreads();

        // ---- reduce level 1: 8 segs of 32 lanes per row ----
        {
            const int row = tid & (PR - 1);
            const int seg = tid >> 5;               // 0..7
            float s0 = 0.f, s1 = 0.f, s2 = 0.f, s3 = 0.f;
            #pragma unroll
            for (int i = 0; i < 32; i += 4) {
                s0 += part[row][seg * 32 + i + 0];
                s1 += part[row][seg * 32 + i + 1];
                s2 += part[row][seg * 32 + i + 2];
                s3 += part[row][seg * 32 + i + 3];
            }
            part2[row][seg] = (s0 + s1) + (s2 + s3);
        }
        __syncthreads();

        // ---- reduce level 2 + global accumulate (4 FG blocks per row) ----
        if (tid < PR) {
            float s = 0.f;
            #pragma unroll
            for (int s8 = 0; s8 < 8; ++s8) s += part2[tid][s8];
            atomicAdd(&out[row0 + ph + tid], s);
        }
        __syncthreads();   // protect part2 (and part) before next phase
    }
}

extern "C" void kernel_launch(void* const* d_in, const int* in_sizes, int n_in,
                              void* d_out, int out_size, void* d_ws, size_t ws_size,
                              hipStream_t stream) {
    const float* x    = (const float*)d_in[0];
    const float* W1   = (const float*)d_in[1];
    const float* b1   = (const float*)d_in[2];
    const float* W2   = (const float*)d_in[3];
    const float* b2   = (const float*)d_in[4];
    const float* bias = (const float*)d_in[5];
    float* out = (float*)d_out;

    nam_init<<<BATCH / BLOCK, BLOCK, 0, stream>>>(out, bias);
    nam_main<<<RB * FG, BLOCK, 0, stream>>>(x, W1, b1, W2, b2, out);
}

// Round 3
// 32.553 us; speedup vs baseline: 1.5569x; 1.1289x over previous
//
#include <hip/hip_runtime.h>

// NeuralAdditiveModel: out[b] = bias + sum_f ( b2[f] + sum_h relu(x[b,f]*W1[f,h]+b1[f,h]) * W2[f,h] )
// x: [16384, 1024] f32, W1/b1/W2: [1024,16] f32, b2: [1024], bias: [1]. out: [16384] f32.
//
// Mapping: lane owns a FEATURE (48 params in VGPRs); 32 rows per block with an
// 8-deep rotating x-prefetch; 1-step shfl pair-reduce -> small LDS -> 1 barrier;
// 3-step shfl final reduce -> one wide atomicAdd per wave. b2/bias pre-folded
// into out by the init kernel.

constexpr int BATCH = 16384;
constexpr int NF    = 1024;
constexpr int HID   = 16;

constexpr int BLOCK = 256;         // 4 waves
constexpr int FG    = 4;           // feature-dim split across blocks
constexpr int FPB   = NF / FG;     // 256 features per block (1 per thread)
constexpr int R     = 32;          // rows per block
constexpr int RB    = BATCH / R;   // 512 row blocks
constexpr int PF    = 8;           // x prefetch depth (must divide R, power of 2)
constexpr int CSTR  = 132;         // part[] row stride in dwords (128 cols + 4 pad)

__global__ __launch_bounds__(BLOCK) void nam_init(float* __restrict__ out,
                                                  const float* __restrict__ b2,
                                                  const float* __restrict__ bias) {
    __shared__ float red[BLOCK / 64];
    const int tid = threadIdx.x;
    // every block computes sum(b2) (tiny, L2-resident)
    float s = 0.f;
    #pragma unroll
    for (int k = 0; k < NF / BLOCK; ++k) s += b2[k * BLOCK + tid];
    #pragma unroll
    for (int off = 32; off >= 1; off >>= 1) s += __shfl_xor(s, off, 64);
    if ((tid & 63) == 0) red[tid >> 6] = s;
    __syncthreads();
    const float tot = (red[0] + red[1]) + (red[2] + red[3]);
    out[blockIdx.x * BLOCK + tid] = bias[0] + tot;
}

__global__ __launch_bounds__(BLOCK, 6) void nam_main(const float* __restrict__ x,
                                                     const float* __restrict__ W1,
                                                     const float* __restrict__ b1,
                                                     const float* __restrict__ W2,
                                                     float* __restrict__ out) {
    __shared__ float part[R * CSTR];   // 16896 B

    const int tid  = threadIdx.x;
    const int rb   = blockIdx.x & (RB - 1);   // row block
    const int fg   = blockIdx.x >> 9;         // feature group (blockIdx.x / RB)
    const int row0 = rb * R;
    const int f    = fg * FPB + tid;          // this lane's feature

    // ---- params in VGPRs (once per block) ----
    float w1[HID], bb[HID], w2[HID];
    #pragma unroll
    for (int i = 0; i < HID / 4; ++i) {
        *reinterpret_cast<float4*>(&w1[4 * i]) =
            *reinterpret_cast<const float4*>(W1 + (size_t)f * HID + 4 * i);
        *reinterpret_cast<float4*>(&bb[4 * i]) =
            *reinterpret_cast<const float4*>(b1 + (size_t)f * HID + 4 * i);
        *reinterpret_cast<float4*>(&w2[4 * i]) =
            *reinterpret_cast<const float4*>(W2 + (size_t)f * HID + 4 * i);
    }

    // ---- 8-deep rotating prefetch of x (fully unrolled -> static indices) ----
    const float* __restrict__ xp = x + (size_t)row0 * NF + f;
    float xv[PF];
    #pragma unroll
    for (int i = 0; i < PF; ++i) xv[i] = xp[(size_t)i * NF];

    #pragma unroll
    for (int r = 0; r < R; ++r) {
        const float v = xv[r & (PF - 1)];
        if (r + PF < R) xv[r & (PF - 1)] = xp[(size_t)(r + PF) * NF];

        float g0 = 0.f, g1 = 0.f, g2 = 0.f, g3 = 0.f;
        #pragma unroll
        for (int h = 0; h < HID; h += 4) {
            g0 = fmaf(fmaxf(fmaf(v, w1[h + 0], bb[h + 0]), 0.f), w2[h + 0], g0);
            g1 = fmaf(fmaxf(fmaf(v, w1[h + 1], bb[h + 1]), 0.f), w2[h + 1], g1);
            g2 = fmaf(fmaxf(fmaf(v, w1[h + 2], bb[h + 2]), 0.f), w2[h + 2], g2);
            g3 = fmaf(fmaxf(fmaf(v, w1[h + 3], bb[h + 3]), 0.f), w2[h + 3], g3);
        }
        float pv = (g0 + g1) + (g2 + g3);

        // pair-reduce (lanes 2k,2k+1) then even lanes write -> halves LDS
        pv += __shfl_xor(pv, 1, 64);
        if ((tid & 1) == 0) part[r * CSTR + (tid >> 1)] = pv;   // conflict-free
    }
    __syncthreads();

    // ---- final reduce: 8 lanes per row, 16 strided reads each (2-way max) ----
    {
        const int row = tid >> 3;          // 0..31
        const int j   = tid & 7;           // 0..7
        float s = 0.f;
        #pragma unroll
        for (int i = 0; i < 16; ++i) s += part[row * CSTR + j + 8 * i];
        s += __shfl_xor(s, 1, 64);
        s += __shfl_xor(s, 2, 64);
        s += __shfl_xor(s, 4, 64);
        if (j == 0) atomicAdd(&out[row0 + row], s);  // 8 consecutive addrs/wave
    }
}

extern "C" void kernel_launch(void* const* d_in, const int* in_sizes, int n_in,
                              void* d_out, int out_size, void* d_ws, size_t ws_size,
                              hipStream_t stream) {
    const float* x    = (const float*)d_in[0];
    const float* W1   = (const float*)d_in[1];
    const float* b1   = (const float*)d_in[2];
    const float* W2   = (const float*)d_in[3];
    const float* b2   = (const float*)d_in[4];
    const float* bias = (const float*)d_in[5];
    float* out = (float*)d_out;

    nam_init<<<BATCH / BLOCK, BLOCK, 0, stream>>>(out, b2, bias);
    nam_main<<<RB * FG, BLOCK, 0, stream>>>(x, W1, b1, W2, out);
}